// Round 9
// baseline (3885.310 us; speedup 1.0000x reference)
//
#include <hip/hip_runtime.h>
#include <cstdint>
#include <cstddef>

typedef unsigned short u16;
typedef unsigned int   u32;
typedef long long      i64;

#define N_NODES 50000
#define N_EDGES 1600000
#define DIM     128
#define NHEADS  4
#define NEG_SLOPE 0.2f

__device__ __forceinline__ float b2f(u16 u) {
    union { u32 u; float f; } v; v.u = ((u32)u) << 16; return v.f;
}
__device__ __forceinline__ u16 f2b(float f) {
    union { float f; u32 u; } v; v.f = f;
    u32 u = v.u;
    u32 r = (u + 0x7fffu + ((u >> 16) & 1u)) >> 16;
    return (u16)r;
}
__device__ __forceinline__ float leaky(float v) {
    return v >= 0.f ? v : NEG_SLOPE * v;
}
__device__ __forceinline__ u32 fkey(float f) {
    union { float f; u32 u; } v; v.f = f;
    return (v.u & 0x80000000u) ? ~v.u : (v.u | 0x80000000u);
}
__device__ __forceinline__ float funkey(u32 k) {
    union { u32 u; float f; } v;
    v.u = (k & 0x80000000u) ? (k ^ 0x80000000u) : ~k;
    return v.f;
}
// f=1: fp32 storage; f=0: packed bf16
__device__ __forceinline__ float fload(const void* p, int f, int idx) {
    return f ? ((const float*)p)[idx] : b2f(((const u16*)p)[idx]);
}
// edge_index stored (2, E) row-major: elem[e]=row_e, elem[E+e]=col_e
__device__ __forceinline__ int eload(const void* ei, int f64, int idx) {
    return f64 ? (int)((const i64*)ei)[idx] : ((const int*)ei)[idx];
}

// ---------------------------------------------------------------------------
// K0: storage detection. flags: [0]=x [1]=Wq [2]=Wk [3]=Wl [4]=bl [5]=ei-int64
// ---------------------------------------------------------------------------
__device__ __forceinline__ int fp32_vote(const u32* p, int K, int lane) {
    int bad = 0;
    for (int i = lane; i < K; i += 64) {
        const u32 w = p[i];
        const u16 lo = (u16)(w & 0xffff);
        const float v = b2f(lo);
        if (lo == 0 || !(fabsf(v) < 1e4f)) ++bad;
    }
    #pragma unroll
    for (int off = 32; off > 0; off >>= 1) bad += __shfl_down(bad, off);
    return bad;
}

__global__ __launch_bounds__(64) void detect_all_kernel(
    const u32* __restrict__ x,  const u32* __restrict__ wq,
    const u32* __restrict__ wk, const u32* __restrict__ wl,
    const u32* __restrict__ bl, const u32* __restrict__ ei,
    int* __restrict__ flags)
{
    const int lane = threadIdx.x;
    int b;
    b = fp32_vote(x,  256, lane); if (lane == 0) flags[0] = (b > 64);
    b = fp32_vote(wq, 128, lane); if (lane == 0) flags[1] = (b > 32);
    b = fp32_vote(wk, 128, lane); if (lane == 0) flags[2] = (b > 32);
    b = fp32_vote(wl, 256, lane); if (lane == 0) flags[3] = (b > 64);
    b = fp32_vote(bl,  64, lane); if (lane == 0) flags[4] = (b > 16);
    int z = 0;
    for (int i = lane; i < 256; i += 64)
        if (ei[2 * i + 1] == 0) ++z;
    #pragma unroll
    for (int off = 32; off > 0; off >>= 1) z += __shfl_down(z, off);
    if (lane == 0) flags[5] = (z > 128);
}

// ---------------------------------------------------------------------------
#define W_TOTAL (512 + 512 + 16384 + 128)
__global__ __launch_bounds__(256) void canon_w_kernel(
    const void* __restrict__ Wq, const void* __restrict__ Wk,
    const void* __restrict__ Wl, const void* __restrict__ bl,
    const int* __restrict__ flags, float* __restrict__ wf)
{
    const int i = blockIdx.x * 256 + threadIdx.x;
    if (i >= W_TOTAL) return;
    const void* src; int j, f;
    if (i < 512)         { src = Wq; j = i;         f = flags[1]; }
    else if (i < 1024)   { src = Wk; j = i - 512;   f = flags[2]; }
    else if (i < 17408)  { src = Wl; j = i - 1024;  f = flags[3]; }
    else                 { src = bl; j = i - 17408; f = flags[4]; }
    wf[i] = fload(src, f, j);
}

// ---------------------------------------------------------------------------
// K1: h_proj (bf16 storage) = x @ Wl^T + bl
// ---------------------------------------------------------------------------
#define NPB 8
__global__ __launch_bounds__(128) void proj_kernel(
    const void* __restrict__ x, const int* __restrict__ flags,
    const float* __restrict__ wf, u16* __restrict__ h_projb)
{
    __shared__ u16  sWT[DIM * DIM];
    __shared__ float sx[DIM];
    const int t = threadIdx.x;
    const int fx = flags[0];
    const float* Wl = wf + 1024;
    const float* bl = wf + 17408;

    for (int i = t; i < DIM * DIM; i += 128) {
        const int o = i & 127;
        const int k = i >> 7;
        sWT[k * DIM + o] = f2b(Wl[o * DIM + k]);
    }
    const float blv = bl[t];

    for (int rep = 0; rep < NPB; ++rep) {
        const int n = blockIdx.x * NPB + rep;
        __syncthreads();
        sx[t] = fload(x, fx, n * DIM + t);
        __syncthreads();
        float acc0 = blv, acc1 = 0.f;
        #pragma unroll 8
        for (int k = 0; k < DIM; k += 2) {
            acc0 = fmaf(sx[k],     b2f(sWT[k * DIM + t]),       acc0);
            acc1 = fmaf(sx[k + 1], b2f(sWT[(k + 1) * DIM + t]), acc1);
        }
        h_projb[n * DIM + t] = f2b(acc0 + acc1);
    }
}

// ---------------------------------------------------------------------------
// K2: h_q = x@Wq^T, k_act = leaky(x@Wk^T)  (fp32 path)
// ---------------------------------------------------------------------------
__global__ __launch_bounds__(256) void qk_kernel(
    const void* __restrict__ x, const int* __restrict__ flags,
    const float* __restrict__ wf,
    float* __restrict__ h_q, float* __restrict__ k_act)
{
    const int wave = threadIdx.x >> 6, lane = threadIdx.x & 63;
    const int n = blockIdx.x * 4 + wave;
    if (n >= N_NODES) return;
    const int fx = flags[0];
    const float x0 = fload(x, fx, n * DIM + 2 * lane);
    const float x1 = fload(x, fx, n * DIM + 2 * lane + 1);
    #pragma unroll
    for (int h = 0; h < NHEADS; ++h) {
        const float qx = wf[h * DIM + 2 * lane];
        const float qy = wf[h * DIM + 2 * lane + 1];
        const float kx = wf[512 + h * DIM + 2 * lane];
        const float ky = wf[512 + h * DIM + 2 * lane + 1];
        float pq = x0 * qx + x1 * qy;
        float pk = x0 * kx + x1 * ky;
        #pragma unroll
        for (int off = 32; off > 0; off >>= 1) {
            pq += __shfl_down(pq, off);
            pk += __shfl_down(pk, off);
        }
        if (lane == 0) {
            h_q[n * NHEADS + h]   = pq;
            k_act[n * NHEADS + h] = leaky(pk);
        }
    }
}

// ---------------------------------------------------------------------------
__global__ __launch_bounds__(256) void qagg_atomic_kernel(
    const void* __restrict__ ei, const int* __restrict__ flags,
    const float* __restrict__ h_q, float* __restrict__ q_agg)
{
    const int e = blockIdx.x * 256 + threadIdx.x;
    if (e >= N_EDGES) return;
    const int fe = flags[5];
    const int r = eload(ei, fe, e);
    const int c = eload(ei, fe, N_EDGES + e);
    #pragma unroll
    for (int h = 0; h < NHEADS; ++h)
        atomicAdd(&q_agg[r * NHEADS + h], h_q[c * NHEADS + h]);
}

__global__ __launch_bounds__(256) void smax_kernel(
    const void* __restrict__ ei, const int* __restrict__ flags,
    const float* __restrict__ k_act, const float* __restrict__ q_agg,
    u32* __restrict__ maxkey)
{
    const int e = blockIdx.x * 256 + threadIdx.x;
    if (e >= N_EDGES) return;
    const int fe = flags[5];
    const int r = eload(ei, fe, e);
    const int c = eload(ei, fe, N_EDGES + e);
    #pragma unroll
    for (int h = 0; h < NHEADS; ++h) {
        const float sc = k_act[r * NHEADS + h] * q_agg[c * NHEADS + h];
        atomicMax(&maxkey[r * NHEADS + h], fkey(sc));
    }
}

__global__ __launch_bounds__(256) void sumexp_kernel(
    const void* __restrict__ ei, const int* __restrict__ flags,
    const float* __restrict__ k_act, const float* __restrict__ q_agg,
    const u32* __restrict__ maxkey, float* __restrict__ sumex)
{
    const int e = blockIdx.x * 256 + threadIdx.x;
    if (e >= N_EDGES) return;
    const int fe = flags[5];
    const int r = eload(ei, fe, e);
    const int c = eload(ei, fe, N_EDGES + e);
    #pragma unroll
    for (int h = 0; h < NHEADS; ++h) {
        const float sc = k_act[r * NHEADS + h] * q_agg[c * NHEADS + h];
        const float mx = funkey(maxkey[r * NHEADS + h]);
        atomicAdd(&sumex[r * NHEADS + h], __expf(sc - mx));
    }
}

__global__ __launch_bounds__(256) void alpha_kernel(
    const void* __restrict__ ei, const int* __restrict__ flags,
    const float* __restrict__ k_act, const float* __restrict__ q_agg,
    const u32* __restrict__ maxkey, const float* __restrict__ sumex,
    u16* __restrict__ alpha_b)
{
    const int e = blockIdx.x * 256 + threadIdx.x;
    if (e >= N_EDGES) return;
    const int fe = flags[5];
    const int r = eload(ei, fe, e);
    const int c = eload(ei, fe, N_EDGES + e);
    float a = 0.f;
    #pragma unroll
    for (int h = 0; h < NHEADS; ++h) {
        const float sc = k_act[r * NHEADS + h] * q_agg[c * NHEADS + h];
        const float mx = funkey(maxkey[r * NHEADS + h]);
        const float sm = sumex[r * NHEADS + h];
        a += __expf(sc - mx) / (sm + 1e-8f);
    }
    alpha_b[e] = f2b(0.25f * a);
}

__global__ __launch_bounds__(256) void scatter_add_kernel(
    const void* __restrict__ ei, const int* __restrict__ flags,
    const u16* __restrict__ alpha_b, const u16* __restrict__ h_projb,
    float* __restrict__ acc)
{
    const long long t = (long long)blockIdx.x * 256 + threadIdx.x;
    if (t >= (long long)N_EDGES * 32) return;
    const int e = (int)(t >> 5);
    const int q = (int)(t & 31);
    const int fe = flags[5];
    const float a = b2f(alpha_b[e]);
    const int r = eload(ei, fe, e);
    const int c = eload(ei, fe, N_EDGES + e);
    const u32* hp = (const u32*)h_projb;
    const u32 w0 = hp[(size_t)c * 64 + 2 * q];
    const u32 w1 = hp[(size_t)c * 64 + 2 * q + 1];
    float* dst = acc + (size_t)r * DIM + 4 * q;
    atomicAdd(dst + 0, a * b2f((u16)(w0 & 0xffff)));
    atomicAdd(dst + 1, a * b2f((u16)(w0 >> 16)));
    atomicAdd(dst + 2, a * b2f((u16)(w1 & 0xffff)));
    atomicAdd(dst + 3, a * b2f((u16)(w1 >> 16)));
}

// ---------------------------------------------------------------------------
// K8: out (FLOAT32!) = leaky(acc)
// ---------------------------------------------------------------------------
__global__ __launch_bounds__(256) void cast_kernel(
    const float* __restrict__ acc, float* __restrict__ out)
{
    const int i = blockIdx.x * 256 + threadIdx.x;
    if (i >= N_NODES * DIM) return;
    out[i] = leaky(acc[i]);
}

// ---------------------------------------------------------------------------
extern "C" void kernel_launch(void* const* d_in, const int* in_sizes, int n_in,
                              void* d_out, int out_size, void* d_ws, size_t ws_size,
                              hipStream_t stream)
{
    const void* x  = d_in[0];
    const void* ei = d_in[1];
    const void* Wq = d_in[2];
    const void* Wk = d_in[3];
    const void* Wl = d_in[4];
    const void* bl = d_in[5];
    float* out = (float*)d_out;   // reference output dtype = float32

    char* ws = (char*)d_ws;
    size_t off = 0;
    auto alloc = [&](size_t bytes) -> size_t {
        off = (off + 255) & ~(size_t)255;
        size_t o = off; off += bytes; return o;
    };
    const size_t o_flag  = alloc(256);
    const size_t o_wf    = alloc((size_t)W_TOTAL * sizeof(float));
    const size_t o_hq    = alloc((size_t)N_NODES * NHEADS * sizeof(float));
    const size_t o_kact  = alloc((size_t)N_NODES * NHEADS * sizeof(float));
    const size_t o_qagg  = alloc((size_t)N_NODES * NHEADS * sizeof(float)); // zeroed
    const size_t o_maxk  = alloc((size_t)N_NODES * NHEADS * sizeof(u32));   // zeroed
    const size_t o_sumex = alloc((size_t)N_NODES * NHEADS * sizeof(float)); // zeroed
    const size_t o_hproj = alloc((size_t)N_NODES * DIM * sizeof(u16));
    const size_t o_alpha = alloc((size_t)N_EDGES * sizeof(u16));
    const size_t o_acc   = alloc((size_t)N_NODES * DIM * sizeof(float));    // zeroed
    (void)ws_size;

    int*   flags   = (int*)(ws + o_flag);
    float* wf      = (float*)(ws + o_wf);
    float* h_q     = (float*)(ws + o_hq);
    float* k_act   = (float*)(ws + o_kact);
    float* q_agg   = (float*)(ws + o_qagg);
    u32*   maxkey  = (u32*)(ws + o_maxk);
    float* sumex   = (float*)(ws + o_sumex);
    u16*   h_projb = (u16*)(ws + o_hproj);
    u16*   alpha_b = (u16*)(ws + o_alpha);
    float* acc     = (float*)(ws + o_acc);

    hipMemsetAsync(ws + o_qagg, 0, o_hproj - o_qagg, stream);
    hipMemsetAsync(ws + o_acc, 0, (size_t)N_NODES * DIM * sizeof(float), stream);

    const int EB = (N_EDGES + 255) / 256;
    detect_all_kernel<<<1, 64, 0, stream>>>(
        (const u32*)x, (const u32*)Wq, (const u32*)Wk, (const u32*)Wl,
        (const u32*)bl, (const u32*)ei, flags);
    canon_w_kernel<<<(W_TOTAL + 255) / 256, 256, 0, stream>>>(Wq, Wk, Wl, bl, flags, wf);
    proj_kernel<<<N_NODES / NPB, 128, 0, stream>>>(x, flags, wf, h_projb);
    qk_kernel<<<N_NODES / 4, 256, 0, stream>>>(x, flags, wf, h_q, k_act);
    qagg_atomic_kernel<<<EB, 256, 0, stream>>>(ei, flags, h_q, q_agg);
    smax_kernel<<<EB, 256, 0, stream>>>(ei, flags, k_act, q_agg, maxkey);
    sumexp_kernel<<<EB, 256, 0, stream>>>(ei, flags, k_act, q_agg, maxkey, sumex);
    alpha_kernel<<<EB, 256, 0, stream>>>(ei, flags, k_act, q_agg, maxkey, sumex, alpha_b);
    scatter_add_kernel<<<(int)(((long long)N_EDGES * 32 + 255) / 256), 256, 0, stream>>>(
        ei, flags, alpha_b, h_projb, acc);
    cast_kernel<<<(N_NODES * DIM + 255) / 256, 256, 0, stream>>>(acc, out);
}

// Round 10
// 607.818 us; speedup vs baseline: 6.3922x; 6.3922x over previous
//
#include <hip/hip_runtime.h>
#include <cstdint>
#include <cstddef>

typedef unsigned short u16;
typedef unsigned int   u32;
typedef long long      i64;

#define N_NODES 50000
#define N_EDGES 1600000
#define DIM     128
#define NHEADS  4
#define NEG_SLOPE 0.2f

__device__ __forceinline__ float b2f(u16 u) {
    union { u32 u; float f; } v; v.u = ((u32)u) << 16; return v.f;
}
__device__ __forceinline__ u16 f2b(float f) {
    union { float f; u32 u; } v; v.f = f;
    u32 u = v.u;
    u32 r = (u + 0x7fffu + ((u >> 16) & 1u)) >> 16;
    return (u16)r;
}
__device__ __forceinline__ float leaky(float v) {
    return v >= 0.f ? v : NEG_SLOPE * v;
}
// f=1: fp32 storage; f=0: packed bf16
__device__ __forceinline__ float fload(const void* p, int f, int idx) {
    return f ? ((const float*)p)[idx] : b2f(((const u16*)p)[idx]);
}
// edge_index stored (2, E) row-major: elem[e]=row_e, elem[E+e]=col_e
__device__ __forceinline__ int eload(const void* ei, int f64, int idx) {
    return f64 ? (int)((const i64*)ei)[idx] : ((const int*)ei)[idx];
}

// ---------------------------------------------------------------------------
// K0: storage detection. flags: [0]=x [1]=Wq [2]=Wk [3]=Wl [4]=bl [5]=ei-int64
// (validated in r9)
// ---------------------------------------------------------------------------
__device__ __forceinline__ int fp32_vote(const u32* p, int K, int lane) {
    int bad = 0;
    for (int i = lane; i < K; i += 64) {
        const u32 w = p[i];
        const u16 lo = (u16)(w & 0xffff);
        const float v = b2f(lo);
        if (lo == 0 || !(fabsf(v) < 1e4f)) ++bad;
    }
    #pragma unroll
    for (int off = 32; off > 0; off >>= 1) bad += __shfl_down(bad, off);
    return bad;
}

__global__ __launch_bounds__(64) void detect_all_kernel(
    const u32* __restrict__ x,  const u32* __restrict__ wq,
    const u32* __restrict__ wk, const u32* __restrict__ wl,
    const u32* __restrict__ bl, const u32* __restrict__ ei,
    int* __restrict__ flags)
{
    const int lane = threadIdx.x;
    int b;
    b = fp32_vote(x,  256, lane); if (lane == 0) flags[0] = (b > 64);
    b = fp32_vote(wq, 128, lane); if (lane == 0) flags[1] = (b > 32);
    b = fp32_vote(wk, 128, lane); if (lane == 0) flags[2] = (b > 32);
    b = fp32_vote(wl, 256, lane); if (lane == 0) flags[3] = (b > 64);
    b = fp32_vote(bl,  64, lane); if (lane == 0) flags[4] = (b > 16);
    int z = 0;
    for (int i = lane; i < 256; i += 64)
        if (ei[2 * i + 1] == 0) ++z;
    #pragma unroll
    for (int off = 32; off > 0; off >>= 1) z += __shfl_down(z, off);
    if (lane == 0) flags[5] = (z > 128);
}

// ---------------------------------------------------------------------------
#define W_TOTAL (512 + 512 + 16384 + 128)
__global__ __launch_bounds__(256) void canon_w_kernel(
    const void* __restrict__ Wq, const void* __restrict__ Wk,
    const void* __restrict__ Wl, const void* __restrict__ bl,
    const int* __restrict__ flags, float* __restrict__ wf)
{
    const int i = blockIdx.x * 256 + threadIdx.x;
    if (i >= W_TOTAL) return;
    const void* src; int j, f;
    if (i < 512)         { src = Wq; j = i;         f = flags[1]; }
    else if (i < 1024)   { src = Wk; j = i - 512;   f = flags[2]; }
    else if (i < 17408)  { src = Wl; j = i - 1024;  f = flags[3]; }
    else                 { src = bl; j = i - 17408; f = flags[4]; }
    wf[i] = fload(src, f, j);
}

// ---------------------------------------------------------------------------
// K1: h_proj (bf16 storage) = x @ Wl^T + bl   (validated in r9)
// ---------------------------------------------------------------------------
#define NPB 8
__global__ __launch_bounds__(128) void proj_kernel(
    const void* __restrict__ x, const int* __restrict__ flags,
    const float* __restrict__ wf, u16* __restrict__ h_projb)
{
    __shared__ u16  sWT[DIM * DIM];
    __shared__ float sx[DIM];
    const int t = threadIdx.x;
    const int fx = flags[0];
    const float* Wl = wf + 1024;
    const float* bl = wf + 17408;

    for (int i = t; i < DIM * DIM; i += 128) {
        const int o = i & 127;
        const int k = i >> 7;
        sWT[k * DIM + o] = f2b(Wl[o * DIM + k]);
    }
    const float blv = bl[t];

    for (int rep = 0; rep < NPB; ++rep) {
        const int n = blockIdx.x * NPB + rep;
        __syncthreads();
        sx[t] = fload(x, fx, n * DIM + t);
        __syncthreads();
        float acc0 = blv, acc1 = 0.f;
        #pragma unroll 8
        for (int k = 0; k < DIM; k += 2) {
            acc0 = fmaf(sx[k],     b2f(sWT[k * DIM + t]),       acc0);
            acc1 = fmaf(sx[k + 1], b2f(sWT[(k + 1) * DIM + t]), acc1);
        }
        h_projb[n * DIM + t] = f2b(acc0 + acc1);
    }
}

// ---------------------------------------------------------------------------
// K2: h_q = x@Wq^T, k_act = leaky(x@Wk^T)   (validated in r9)
// ---------------------------------------------------------------------------
__global__ __launch_bounds__(256) void qk_kernel(
    const void* __restrict__ x, const int* __restrict__ flags,
    const float* __restrict__ wf,
    float* __restrict__ h_q, float* __restrict__ k_act)
{
    const int wave = threadIdx.x >> 6, lane = threadIdx.x & 63;
    const int n = blockIdx.x * 4 + wave;
    if (n >= N_NODES) return;
    const int fx = flags[0];
    const float x0 = fload(x, fx, n * DIM + 2 * lane);
    const float x1 = fload(x, fx, n * DIM + 2 * lane + 1);
    #pragma unroll
    for (int h = 0; h < NHEADS; ++h) {
        const float qx = wf[h * DIM + 2 * lane];
        const float qy = wf[h * DIM + 2 * lane + 1];
        const float kx = wf[512 + h * DIM + 2 * lane];
        const float ky = wf[512 + h * DIM + 2 * lane + 1];
        float pq = x0 * qx + x1 * qy;
        float pk = x0 * kx + x1 * ky;
        #pragma unroll
        for (int off = 32; off > 0; off >>= 1) {
            pq += __shfl_down(pq, off);
            pk += __shfl_down(pk, off);
        }
        if (lane == 0) {
            h_q[n * NHEADS + h]   = pq;
            k_act[n * NHEADS + h] = leaky(pk);
        }
    }
}

// ---------------------------------------------------------------------------
// K3: in-degree histogram (int atomics, cheap)
// ---------------------------------------------------------------------------
__global__ __launch_bounds__(256) void hist_kernel(
    const void* __restrict__ ei, const int* __restrict__ flags,
    int* __restrict__ deg)
{
    const int e = blockIdx.x * 256 + threadIdx.x;
    if (e < N_EDGES) atomicAdd(&deg[eload(ei, flags[5], e)], 1);
}

// ---------------------------------------------------------------------------
// K4: exclusive scan of deg -> offsets (single 1024-thread block)
// ---------------------------------------------------------------------------
__global__ __launch_bounds__(1024) void scan_kernel(
    const int* __restrict__ deg, int* __restrict__ offsets)
{
    __shared__ int part[1024];
    const int t = threadIdx.x;
    const int CH = (N_NODES + 1023) / 1024;   // 49
    const int base = t * CH;
    int s = 0;
    for (int i = 0; i < CH; ++i) {
        const int idx = base + i;
        if (idx < N_NODES) s += deg[idx];
    }
    part[t] = s;
    __syncthreads();
    for (int off = 1; off < 1024; off <<= 1) {
        const int v = (t >= off) ? part[t - off] : 0;
        __syncthreads();
        part[t] += v;
        __syncthreads();
    }
    int run = part[t] - s;
    for (int i = 0; i < CH; ++i) {
        const int idx = base + i;
        if (idx < N_NODES) { offsets[idx] = run; run += deg[idx]; }
    }
    if (t == 1023) offsets[N_NODES] = part[1023];
}

// ---------------------------------------------------------------------------
// K5: scatter edges into CSR slots (by destination; 1.6M int atomics)
// ---------------------------------------------------------------------------
__global__ __launch_bounds__(256) void csr_kernel(
    const void* __restrict__ ei, const int* __restrict__ flags,
    const int* __restrict__ offsets, int* __restrict__ cursor,
    int* __restrict__ csr_col)
{
    const int e = blockIdx.x * 256 + threadIdx.x;
    if (e >= N_EDGES) return;
    const int fe = flags[5];
    const int r = eload(ei, fe, e);
    const int c = eload(ei, fe, N_EDGES + e);
    const int p = atomicAdd(&cursor[r], 1);
    csr_col[offsets[r] + p] = c;
}

// ---------------------------------------------------------------------------
// K6: q_agg[n] = sum over incoming edges of h_q[col]  (wave per node, no atomics)
// ---------------------------------------------------------------------------
__global__ __launch_bounds__(256) void qagg_kernel(
    const int* __restrict__ offsets, const int* __restrict__ csr_col,
    const float* __restrict__ h_q, float* __restrict__ q_agg)
{
    const int wave = threadIdx.x >> 6, lane = threadIdx.x & 63;
    const int n = blockIdx.x * 4 + wave;
    if (n >= N_NODES) return;
    const int s0 = offsets[n], s1 = offsets[n + 1];
    float a0 = 0.f, a1 = 0.f, a2 = 0.f, a3 = 0.f;
    for (int s = s0 + lane; s < s1; s += 64) {
        const int c = csr_col[s];
        const float4 q = ((const float4*)h_q)[c];
        a0 += q.x; a1 += q.y; a2 += q.z; a3 += q.w;
    }
    #pragma unroll
    for (int off = 32; off > 0; off >>= 1) {
        a0 += __shfl_down(a0, off); a1 += __shfl_down(a1, off);
        a2 += __shfl_down(a2, off); a3 += __shfl_down(a3, off);
    }
    if (lane == 0) ((float4*)q_agg)[n] = make_float4(a0, a1, a2, a3);
}

// ---------------------------------------------------------------------------
// K7: fused online softmax + weighted aggregation -> out fp32
//     one wave per node, no atomics, no per-edge workspace
// ---------------------------------------------------------------------------
__global__ __launch_bounds__(256) void attn_kernel(
    const int* __restrict__ offsets, const int* __restrict__ csr_col,
    const float* __restrict__ k_act, const float* __restrict__ q_agg,
    const u16* __restrict__ h_projb, float* __restrict__ out)
{
    const int wave = threadIdx.x >> 6, lane = threadIdx.x & 63;
    const int n = blockIdx.x * 4 + wave;
    if (n >= N_NODES) return;
    const int s0 = offsets[n], s1 = offsets[n + 1];
    const float4 k4 = ((const float4*)k_act)[n];

    // ---- pass A: online softmax (m, t) per head, per lane ----
    float m0 = -1e30f, m1 = -1e30f, m2 = -1e30f, m3 = -1e30f;
    float t0 = 0.f, t1 = 0.f, t2 = 0.f, t3 = 0.f;
    for (int s = s0 + lane; s < s1; s += 64) {
        const int c = csr_col[s];
        const float4 q = ((const float4*)q_agg)[c];
        const float sc0 = k4.x * q.x, sc1 = k4.y * q.y;
        const float sc2 = k4.z * q.z, sc3 = k4.w * q.w;
        float nm;
        nm = fmaxf(m0, sc0); t0 = t0 * __expf(m0 - nm) + __expf(sc0 - nm); m0 = nm;
        nm = fmaxf(m1, sc1); t1 = t1 * __expf(m1 - nm) + __expf(sc1 - nm); m1 = nm;
        nm = fmaxf(m2, sc2); t2 = t2 * __expf(m2 - nm) + __expf(sc2 - nm); m2 = nm;
        nm = fmaxf(m3, sc3); t3 = t3 * __expf(m3 - nm) + __expf(sc3 - nm); m3 = nm;
    }
    #pragma unroll
    for (int off = 32; off > 0; off >>= 1) {
        float om, ot, nm;
        om = __shfl_xor(m0, off); ot = __shfl_xor(t0, off);
        nm = fmaxf(m0, om); t0 = t0 * __expf(m0 - nm) + ot * __expf(om - nm); m0 = nm;
        om = __shfl_xor(m1, off); ot = __shfl_xor(t1, off);
        nm = fmaxf(m1, om); t1 = t1 * __expf(m1 - nm) + ot * __expf(om - nm); m1 = nm;
        om = __shfl_xor(m2, off); ot = __shfl_xor(t2, off);
        nm = fmaxf(m2, om); t2 = t2 * __expf(m2 - nm) + ot * __expf(om - nm); m2 = nm;
        om = __shfl_xor(m3, off); ot = __shfl_xor(t3, off);
        nm = fmaxf(m3, om); t3 = t3 * __expf(m3 - nm) + ot * __expf(om - nm); m3 = nm;
    }
    const float r0 = 0.25f / (t0 + 1e-8f), r1 = 0.25f / (t1 + 1e-8f);
    const float r2 = 0.25f / (t2 + 1e-8f), r3 = 0.25f / (t3 + 1e-8f);

    // ---- pass B: alpha per slot (exact recompute) + broadcast accumulate ----
    float acc0 = 0.f, acc1 = 0.f;   // dims 2*lane, 2*lane+1
    const u32* hp = (const u32*)h_projb;
    for (int base = s0; base < s1; base += 64) {
        const int s = base + lane;
        int   c_s = 0;
        float a_s = 0.f;
        if (s < s1) {
            c_s = csr_col[s];
            const float4 q = ((const float4*)q_agg)[c_s];
            a_s = __expf(k4.x * q.x - m0) * r0 + __expf(k4.y * q.y - m1) * r1
                + __expf(k4.z * q.z - m2) * r2 + __expf(k4.w * q.w - m3) * r3;
        }
        const int cnt = min(64, s1 - base);
        int j = 0;
        for (; j + 3 < cnt; j += 4) {
            const int   c0 = __shfl(c_s, j),     c1 = __shfl(c_s, j + 1);
            const int   c2 = __shfl(c_s, j + 2), c3 = __shfl(c_s, j + 3);
            const float a0 = __shfl(a_s, j),     a1 = __shfl(a_s, j + 1);
            const float a2 = __shfl(a_s, j + 2), a3 = __shfl(a_s, j + 3);
            const u32 w0 = hp[(size_t)c0 * 64 + lane];
            const u32 w1 = hp[(size_t)c1 * 64 + lane];
            const u32 w2 = hp[(size_t)c2 * 64 + lane];
            const u32 w3 = hp[(size_t)c3 * 64 + lane];
            acc0 = fmaf(a0, b2f((u16)(w0 & 0xffff)), acc0);
            acc1 = fmaf(a0, b2f((u16)(w0 >> 16)),    acc1);
            acc0 = fmaf(a1, b2f((u16)(w1 & 0xffff)), acc0);
            acc1 = fmaf(a1, b2f((u16)(w1 >> 16)),    acc1);
            acc0 = fmaf(a2, b2f((u16)(w2 & 0xffff)), acc0);
            acc1 = fmaf(a2, b2f((u16)(w2 >> 16)),    acc1);
            acc0 = fmaf(a3, b2f((u16)(w3 & 0xffff)), acc0);
            acc1 = fmaf(a3, b2f((u16)(w3 >> 16)),    acc1);
        }
        for (; j < cnt; ++j) {
            const int   c = __shfl(c_s, j);
            const float a = __shfl(a_s, j);
            const u32   w = hp[(size_t)c * 64 + lane];
            acc0 = fmaf(a, b2f((u16)(w & 0xffff)), acc0);
            acc1 = fmaf(a, b2f((u16)(w >> 16)),    acc1);
        }
    }
    ((float2*)out)[(size_t)n * 64 + lane] =
        make_float2(leaky(acc0), leaky(acc1));
}

// ---------------------------------------------------------------------------
extern "C" void kernel_launch(void* const* d_in, const int* in_sizes, int n_in,
                              void* d_out, int out_size, void* d_ws, size_t ws_size,
                              hipStream_t stream)
{
    const void* x  = d_in[0];
    const void* ei = d_in[1];
    const void* Wq = d_in[2];
    const void* Wk = d_in[3];
    const void* Wl = d_in[4];
    const void* bl = d_in[5];
    float* out = (float*)d_out;   // reference output dtype = float32

    char* ws = (char*)d_ws;
    size_t off = 0;
    auto alloc = [&](size_t bytes) -> size_t {
        off = (off + 255) & ~(size_t)255;
        size_t o = off; off += bytes; return o;
    };
    const size_t o_flag  = alloc(256);
    const size_t o_wf    = alloc((size_t)W_TOTAL * sizeof(float));
    const size_t o_hq    = alloc((size_t)N_NODES * NHEADS * sizeof(float));
    const size_t o_kact  = alloc((size_t)N_NODES * NHEADS * sizeof(float));
    const size_t o_qagg  = alloc((size_t)N_NODES * NHEADS * sizeof(float));
    const size_t o_hproj = alloc((size_t)N_NODES * DIM * sizeof(u16));
    const size_t o_deg   = alloc((size_t)N_NODES * sizeof(int));   // zeroed
    const size_t o_cur   = alloc((size_t)N_NODES * sizeof(int));   // zeroed
    const size_t o_offs  = alloc((size_t)(N_NODES + 1) * sizeof(int));
    const size_t o_csr   = alloc((size_t)N_EDGES * sizeof(int));
    (void)ws_size;   // ~22 MB, proven ample in r7 (ws_size >= 45.9 MB)

    int*   flags   = (int*)(ws + o_flag);
    float* wf      = (float*)(ws + o_wf);
    float* h_q     = (float*)(ws + o_hq);
    float* k_act   = (float*)(ws + o_kact);
    float* q_agg   = (float*)(ws + o_qagg);
    u16*   h_projb = (u16*)(ws + o_hproj);
    int*   deg     = (int*)(ws + o_deg);
    int*   cursor  = (int*)(ws + o_cur);
    int*   offsets = (int*)(ws + o_offs);
    int*   csr_col = (int*)(ws + o_csr);

    hipMemsetAsync(ws + o_deg, 0, o_offs - o_deg, stream);   // deg + cursor

    const int EB = (N_EDGES + 255) / 256;
    detect_all_kernel<<<1, 64, 0, stream>>>(
        (const u32*)x, (const u32*)Wq, (const u32*)Wk, (const u32*)Wl,
        (const u32*)bl, (const u32*)ei, flags);
    canon_w_kernel<<<(W_TOTAL + 255) / 256, 256, 0, stream>>>(Wq, Wk, Wl, bl, flags, wf);
    proj_kernel<<<N_NODES / NPB, 128, 0, stream>>>(x, flags, wf, h_projb);
    qk_kernel<<<N_NODES / 4, 256, 0, stream>>>(x, flags, wf, h_q, k_act);
    hist_kernel<<<EB, 256, 0, stream>>>(ei, flags, deg);
    scan_kernel<<<1, 1024, 0, stream>>>(deg, offsets);
    csr_kernel<<<EB, 256, 0, stream>>>(ei, flags, offsets, cursor, csr_col);
    qagg_kernel<<<N_NODES / 4, 256, 0, stream>>>(offsets, csr_col, h_q, q_agg);
    attn_kernel<<<N_NODES / 4, 256, 0, stream>>>(offsets, csr_col, k_act, q_agg,
                                                 h_projb, out);
}

// Round 11
// 545.554 us; speedup vs baseline: 7.1218x; 1.1141x over previous
//
#include <hip/hip_runtime.h>
#include <cstdint>
#include <cstddef>

typedef unsigned short u16;
typedef unsigned int   u32;
typedef long long      i64;

#define N_NODES 50000
#define N_EDGES 1600000
#define DIM     128
#define NHEADS  4
#define NEG_SLOPE 0.2f

__device__ __forceinline__ float b2f(u16 u) {
    union { u32 u; float f; } v; v.u = ((u32)u) << 16; return v.f;
}
__device__ __forceinline__ u16 f2b(float f) {
    union { float f; u32 u; } v; v.f = f;
    u32 u = v.u;
    u32 r = (u + 0x7fffu + ((u >> 16) & 1u)) >> 16;
    return (u16)r;
}
__device__ __forceinline__ float leaky(float v) {
    return v >= 0.f ? v : NEG_SLOPE * v;
}
// f=1: fp32 storage; f=0: packed bf16
__device__ __forceinline__ float fload(const void* p, int f, int idx) {
    return f ? ((const float*)p)[idx] : b2f(((const u16*)p)[idx]);
}
// edge_index stored (2, E) row-major: elem[e]=row_e, elem[E+e]=col_e
__device__ __forceinline__ int eload(const void* ei, int f64, int idx) {
    return f64 ? (int)((const i64*)ei)[idx] : ((const int*)ei)[idx];
}

// ---------------------------------------------------------------------------
// K0: storage detection. flags: [0]=x [1]=Wq [2]=Wk [3]=Wl [4]=bl [5]=ei-int64
// (validated r9/r10)
// ---------------------------------------------------------------------------
__device__ __forceinline__ int fp32_vote(const u32* p, int K, int lane) {
    int bad = 0;
    for (int i = lane; i < K; i += 64) {
        const u32 w = p[i];
        const u16 lo = (u16)(w & 0xffff);
        const float v = b2f(lo);
        if (lo == 0 || !(fabsf(v) < 1e4f)) ++bad;
    }
    #pragma unroll
    for (int off = 32; off > 0; off >>= 1) bad += __shfl_down(bad, off);
    return bad;
}

__global__ __launch_bounds__(64) void detect_all_kernel(
    const u32* __restrict__ x,  const u32* __restrict__ wq,
    const u32* __restrict__ wk, const u32* __restrict__ wl,
    const u32* __restrict__ bl, const u32* __restrict__ ei,
    int* __restrict__ flags)
{
    const int lane = threadIdx.x;
    int b;
    b = fp32_vote(x,  256, lane); if (lane == 0) flags[0] = (b > 64);
    b = fp32_vote(wq, 128, lane); if (lane == 0) flags[1] = (b > 32);
    b = fp32_vote(wk, 128, lane); if (lane == 0) flags[2] = (b > 32);
    b = fp32_vote(wl, 256, lane); if (lane == 0) flags[3] = (b > 64);
    b = fp32_vote(bl,  64, lane); if (lane == 0) flags[4] = (b > 16);
    int z = 0;
    for (int i = lane; i < 256; i += 64)
        if (ei[2 * i + 1] == 0) ++z;
    #pragma unroll
    for (int off = 32; off > 0; off >>= 1) z += __shfl_down(z, off);
    if (lane == 0) flags[5] = (z > 128);
}

// ---------------------------------------------------------------------------
#define W_TOTAL (512 + 512 + 16384 + 128)
__global__ __launch_bounds__(256) void canon_w_kernel(
    const void* __restrict__ Wq, const void* __restrict__ Wk,
    const void* __restrict__ Wl, const void* __restrict__ bl,
    const int* __restrict__ flags, float* __restrict__ wf)
{
    const int i = blockIdx.x * 256 + threadIdx.x;
    if (i >= W_TOTAL) return;
    const void* src; int j, f;
    if (i < 512)         { src = Wq; j = i;         f = flags[1]; }
    else if (i < 1024)   { src = Wk; j = i - 512;   f = flags[2]; }
    else if (i < 17408)  { src = Wl; j = i - 1024;  f = flags[3]; }
    else                 { src = bl; j = i - 17408; f = flags[4]; }
    wf[i] = fload(src, f, j);
}

// ---------------------------------------------------------------------------
// K1 v2: h_proj (bf16 storage) = x @ Wl^T + bl
//   512 threads = 8 waves; 4 nodes in parallel x 8 reps = 32 nodes/block.
//   sWT packed as u32 (2 bf16 k-values) -> ds_read_b32 instead of 2x u16.
//   LDS 34 KB -> 4 blocks/CU -> up to 32 waves/CU.
// ---------------------------------------------------------------------------
#define PB_NODES 32
__global__ __launch_bounds__(512) void proj_kernel(
    const void* __restrict__ x, const int* __restrict__ flags,
    const float* __restrict__ wf, u16* __restrict__ h_projb)
{
    __shared__ u32  sWT32[64 * DIM];     // 32 KB: sWT32[k2*128+o] = bf16(Wl[o][2k2]) | bf16(Wl[o][2k2+1])<<16
    __shared__ float sx[4][DIM];         // 2 KB
    const int t = threadIdx.x;
    const int o = t & 127;               // output dim
    const int g = t >> 7;                // node group 0..3
    const int fx = flags[0];
    const float* Wl = wf + 1024;
    const float* bl = wf + 17408;

    // stage packed Wl^T
    for (int i = t; i < 64 * DIM; i += 512) {
        const int k2 = i >> 7;
        const int oo = i & 127;
        const float w0 = Wl[oo * DIM + 2 * k2];
        const float w1 = Wl[oo * DIM + 2 * k2 + 1];
        sWT32[i] = (u32)f2b(w0) | ((u32)f2b(w1) << 16);
    }
    const float blv = bl[o];

    for (int rep = 0; rep < 8; ++rep) {
        const int n = blockIdx.x * PB_NODES + rep * 4 + g;
        __syncthreads();
        if (n < N_NODES) sx[g][o] = fload(x, fx, n * DIM + o);  // contiguous across block
        __syncthreads();
        if (n >= N_NODES) continue;
        float acc0 = blv, acc1 = 0.f;
        #pragma unroll 8
        for (int k2 = 0; k2 < 64; ++k2) {
            const u32 w = sWT32[k2 * DIM + o];
            acc0 = fmaf(sx[g][2 * k2],     b2f((u16)(w & 0xffff)), acc0);
            acc1 = fmaf(sx[g][2 * k2 + 1], b2f((u16)(w >> 16)),    acc1);
        }
        h_projb[n * DIM + o] = f2b(acc0 + acc1);
    }
}

// ---------------------------------------------------------------------------
// K2: h_q = x@Wq^T, k_act = leaky(x@Wk^T)   (validated r9/r10)
// ---------------------------------------------------------------------------
__global__ __launch_bounds__(256) void qk_kernel(
    const void* __restrict__ x, const int* __restrict__ flags,
    const float* __restrict__ wf,
    float* __restrict__ h_q, float* __restrict__ k_act)
{
    const int wave = threadIdx.x >> 6, lane = threadIdx.x & 63;
    const int n = blockIdx.x * 4 + wave;
    if (n >= N_NODES) return;
    const int fx = flags[0];
    const float x0 = fload(x, fx, n * DIM + 2 * lane);
    const float x1 = fload(x, fx, n * DIM + 2 * lane + 1);
    #pragma unroll
    for (int h = 0; h < NHEADS; ++h) {
        const float qx = wf[h * DIM + 2 * lane];
        const float qy = wf[h * DIM + 2 * lane + 1];
        const float kx = wf[512 + h * DIM + 2 * lane];
        const float ky = wf[512 + h * DIM + 2 * lane + 1];
        float pq = x0 * qx + x1 * qy;
        float pk = x0 * kx + x1 * ky;
        #pragma unroll
        for (int off = 32; off > 0; off >>= 1) {
            pq += __shfl_down(pq, off);
            pk += __shfl_down(pk, off);
        }
        if (lane == 0) {
            h_q[n * NHEADS + h]   = pq;
            k_act[n * NHEADS + h] = leaky(pk);
        }
    }
}

// ---------------------------------------------------------------------------
// K3: in-degree histogram (int atomics, cheap)
// ---------------------------------------------------------------------------
__global__ __launch_bounds__(256) void hist_kernel(
    const void* __restrict__ ei, const int* __restrict__ flags,
    int* __restrict__ deg)
{
    const int e = blockIdx.x * 256 + threadIdx.x;
    if (e < N_EDGES) atomicAdd(&deg[eload(ei, flags[5], e)], 1);
}

// ---------------------------------------------------------------------------
// K4: exclusive scan of deg -> offsets (single 1024-thread block)
// ---------------------------------------------------------------------------
__global__ __launch_bounds__(1024) void scan_kernel(
    const int* __restrict__ deg, int* __restrict__ offsets)
{
    __shared__ int part[1024];
    const int t = threadIdx.x;
    const int CH = (N_NODES + 1023) / 1024;   // 49
    const int base = t * CH;
    int s = 0;
    for (int i = 0; i < CH; ++i) {
        const int idx = base + i;
        if (idx < N_NODES) s += deg[idx];
    }
    part[t] = s;
    __syncthreads();
    for (int off = 1; off < 1024; off <<= 1) {
        const int v = (t >= off) ? part[t - off] : 0;
        __syncthreads();
        part[t] += v;
        __syncthreads();
    }
    int run = part[t] - s;
    for (int i = 0; i < CH; ++i) {
        const int idx = base + i;
        if (idx < N_NODES) { offsets[idx] = run; run += deg[idx]; }
    }
    if (t == 1023) offsets[N_NODES] = part[1023];
}

// ---------------------------------------------------------------------------
// K5: scatter edges into CSR slots (by destination; 1.6M int atomics)
// ---------------------------------------------------------------------------
__global__ __launch_bounds__(256) void csr_kernel(
    const void* __restrict__ ei, const int* __restrict__ flags,
    const int* __restrict__ offsets, int* __restrict__ cursor,
    int* __restrict__ csr_col)
{
    const int e = blockIdx.x * 256 + threadIdx.x;
    if (e >= N_EDGES) return;
    const int fe = flags[5];
    const int r = eload(ei, fe, e);
    const int c = eload(ei, fe, N_EDGES + e);
    const int p = atomicAdd(&cursor[r], 1);
    csr_col[offsets[r] + p] = c;
}

// ---------------------------------------------------------------------------
// K6: q_agg[n] = sum over incoming edges of h_q[col]  (wave per node)
// ---------------------------------------------------------------------------
__global__ __launch_bounds__(256) void qagg_kernel(
    const int* __restrict__ offsets, const int* __restrict__ csr_col,
    const float* __restrict__ h_q, float* __restrict__ q_agg)
{
    const int wave = threadIdx.x >> 6, lane = threadIdx.x & 63;
    const int n = blockIdx.x * 4 + wave;
    if (n >= N_NODES) return;
    const int s0 = offsets[n], s1 = offsets[n + 1];
    float a0 = 0.f, a1 = 0.f, a2 = 0.f, a3 = 0.f;
    for (int s = s0 + lane; s < s1; s += 64) {
        const int c = csr_col[s];
        const float4 q = ((const float4*)h_q)[c];
        a0 += q.x; a1 += q.y; a2 += q.z; a3 += q.w;
    }
    #pragma unroll
    for (int off = 32; off > 0; off >>= 1) {
        a0 += __shfl_down(a0, off); a1 += __shfl_down(a1, off);
        a2 += __shfl_down(a2, off); a3 += __shfl_down(a3, off);
    }
    if (lane == 0) ((float4*)q_agg)[n] = make_float4(a0, a1, a2, a3);
}

// ---------------------------------------------------------------------------
// K7: fused online softmax + weighted aggregation -> out fp32
// ---------------------------------------------------------------------------
__global__ __launch_bounds__(256) void attn_kernel(
    const int* __restrict__ offsets, const int* __restrict__ csr_col,
    const float* __restrict__ k_act, const float* __restrict__ q_agg,
    const u16* __restrict__ h_projb, float* __restrict__ out)
{
    const int wave = threadIdx.x >> 6, lane = threadIdx.x & 63;
    const int n = blockIdx.x * 4 + wave;
    if (n >= N_NODES) return;
    const int s0 = offsets[n], s1 = offsets[n + 1];
    const float4 k4 = ((const float4*)k_act)[n];

    // ---- pass A: online softmax (m, t) per head, per lane ----
    float m0 = -1e30f, m1 = -1e30f, m2 = -1e30f, m3 = -1e30f;
    float t0 = 0.f, t1 = 0.f, t2 = 0.f, t3 = 0.f;
    for (int s = s0 + lane; s < s1; s += 64) {
        const int c = csr_col[s];
        const float4 q = ((const float4*)q_agg)[c];
        const float sc0 = k4.x * q.x, sc1 = k4.y * q.y;
        const float sc2 = k4.z * q.z, sc3 = k4.w * q.w;
        float nm;
        nm = fmaxf(m0, sc0); t0 = t0 * __expf(m0 - nm) + __expf(sc0 - nm); m0 = nm;
        nm = fmaxf(m1, sc1); t1 = t1 * __expf(m1 - nm) + __expf(sc1 - nm); m1 = nm;
        nm = fmaxf(m2, sc2); t2 = t2 * __expf(m2 - nm) + __expf(sc2 - nm); m2 = nm;
        nm = fmaxf(m3, sc3); t3 = t3 * __expf(m3 - nm) + __expf(sc3 - nm); m3 = nm;
    }
    #pragma unroll
    for (int off = 32; off > 0; off >>= 1) {
        float om, ot, nm;
        om = __shfl_xor(m0, off); ot = __shfl_xor(t0, off);
        nm = fmaxf(m0, om); t0 = t0 * __expf(m0 - nm) + ot * __expf(om - nm); m0 = nm;
        om = __shfl_xor(m1, off); ot = __shfl_xor(t1, off);
        nm = fmaxf(m1, om); t1 = t1 * __expf(m1 - nm) + ot * __expf(om - nm); m1 = nm;
        om = __shfl_xor(m2, off); ot = __shfl_xor(t2, off);
        nm = fmaxf(m2, om); t2 = t2 * __expf(m2 - nm) + ot * __expf(om - nm); m2 = nm;
        om = __shfl_xor(m3, off); ot = __shfl_xor(t3, off);
        nm = fmaxf(m3, om); t3 = t3 * __expf(m3 - nm) + ot * __expf(om - nm); m3 = nm;
    }
    const float r0 = 0.25f / (t0 + 1e-8f), r1 = 0.25f / (t1 + 1e-8f);
    const float r2 = 0.25f / (t2 + 1e-8f), r3 = 0.25f / (t3 + 1e-8f);

    // ---- pass B: alpha per slot (exact recompute) + broadcast accumulate ----
    float acc0 = 0.f, acc1 = 0.f;   // dims 2*lane, 2*lane+1
    const u32* hp = (const u32*)h_projb;
    for (int base = s0; base < s1; base += 64) {
        const int s = base + lane;
        int   c_s = 0;
        float a_s = 0.f;
        if (s < s1) {
            c_s = csr_col[s];
            const float4 q = ((const float4*)q_agg)[c_s];
            a_s = __expf(k4.x * q.x - m0) * r0 + __expf(k4.y * q.y - m1) * r1
                + __expf(k4.z * q.z - m2) * r2 + __expf(k4.w * q.w - m3) * r3;
        }
        const int cnt = min(64, s1 - base);
        int j = 0;
        for (; j + 3 < cnt; j += 4) {
            const int   c0 = __shfl(c_s, j),     c1 = __shfl(c_s, j + 1);
            const int   c2 = __shfl(c_s, j + 2), c3 = __shfl(c_s, j + 3);
            const float a0 = __shfl(a_s, j),     a1 = __shfl(a_s, j + 1);
            const float a2 = __shfl(a_s, j + 2), a3 = __shfl(a_s, j + 3);
            const u32 w0 = hp[(size_t)c0 * 64 + lane];
            const u32 w1 = hp[(size_t)c1 * 64 + lane];
            const u32 w2 = hp[(size_t)c2 * 64 + lane];
            const u32 w3 = hp[(size_t)c3 * 64 + lane];
            acc0 = fmaf(a0, b2f((u16)(w0 & 0xffff)), acc0);
            acc1 = fmaf(a0, b2f((u16)(w0 >> 16)),    acc1);
            acc0 = fmaf(a1, b2f((u16)(w1 & 0xffff)), acc0);
            acc1 = fmaf(a1, b2f((u16)(w1 >> 16)),    acc1);
            acc0 = fmaf(a2, b2f((u16)(w2 & 0xffff)), acc0);
            acc1 = fmaf(a2, b2f((u16)(w2 >> 16)),    acc1);
            acc0 = fmaf(a3, b2f((u16)(w3 & 0xffff)), acc0);
            acc1 = fmaf(a3, b2f((u16)(w3 >> 16)),    acc1);
        }
        for (; j < cnt; ++j) {
            const int   c = __shfl(c_s, j);
            const float a = __shfl(a_s, j);
            const u32   w = hp[(size_t)c * 64 + lane];
            acc0 = fmaf(a, b2f((u16)(w & 0xffff)), acc0);
            acc1 = fmaf(a, b2f((u16)(w >> 16)),    acc1);
        }
    }
    ((float2*)out)[(size_t)n * 64 + lane] =
        make_float2(leaky(acc0), leaky(acc1));
}

// ---------------------------------------------------------------------------
extern "C" void kernel_launch(void* const* d_in, const int* in_sizes, int n_in,
                              void* d_out, int out_size, void* d_ws, size_t ws_size,
                              hipStream_t stream)
{
    const void* x  = d_in[0];
    const void* ei = d_in[1];
    const void* Wq = d_in[2];
    const void* Wk = d_in[3];
    const void* Wl = d_in[4];
    const void* bl = d_in[5];
    float* out = (float*)d_out;   // reference output dtype = float32

    char* ws = (char*)d_ws;
    size_t off = 0;
    auto alloc = [&](size_t bytes) -> size_t {
        off = (off + 255) & ~(size_t)255;
        size_t o = off; off += bytes; return o;
    };
    const size_t o_flag  = alloc(256);
    const size_t o_wf    = alloc((size_t)W_TOTAL * sizeof(float));
    const size_t o_hq    = alloc((size_t)N_NODES * NHEADS * sizeof(float));
    const size_t o_kact  = alloc((size_t)N_NODES * NHEADS * sizeof(float));
    const size_t o_qagg  = alloc((size_t)N_NODES * NHEADS * sizeof(float));
    const size_t o_hproj = alloc((size_t)N_NODES * DIM * sizeof(u16));
    const size_t o_deg   = alloc((size_t)N_NODES * sizeof(int));   // zeroed
    const size_t o_cur   = alloc((size_t)N_NODES * sizeof(int));   // zeroed
    const size_t o_offs  = alloc((size_t)(N_NODES + 1) * sizeof(int));
    const size_t o_csr   = alloc((size_t)N_EDGES * sizeof(int));
    (void)ws_size;   // ~22 MB, ws_size proven >= 45.9 MB in r7

    int*   flags   = (int*)(ws + o_flag);
    float* wf      = (float*)(ws + o_wf);
    float* h_q     = (float*)(ws + o_hq);
    float* k_act   = (float*)(ws + o_kact);
    float* q_agg   = (float*)(ws + o_qagg);
    u16*   h_projb = (u16*)(ws + o_hproj);
    int*   deg     = (int*)(ws + o_deg);
    int*   cursor  = (int*)(ws + o_cur);
    int*   offsets = (int*)(ws + o_offs);
    int*   csr_col = (int*)(ws + o_csr);

    hipMemsetAsync(ws + o_deg, 0, o_offs - o_deg, stream);   // deg + cursor

    const int EB = (N_EDGES + 255) / 256;
    detect_all_kernel<<<1, 64, 0, stream>>>(
        (const u32*)x, (const u32*)Wq, (const u32*)Wk, (const u32*)Wl,
        (const u32*)bl, (const u32*)ei, flags);
    canon_w_kernel<<<(W_TOTAL + 255) / 256, 256, 0, stream>>>(Wq, Wk, Wl, bl, flags, wf);
    proj_kernel<<<(N_NODES + PB_NODES - 1) / PB_NODES, 512, 0, stream>>>(
        x, flags, wf, h_projb);
    qk_kernel<<<N_NODES / 4, 256, 0, stream>>>(x, flags, wf, h_q, k_act);
    hist_kernel<<<EB, 256, 0, stream>>>(ei, flags, deg);
    scan_kernel<<<1, 1024, 0, stream>>>(deg, offsets);
    csr_kernel<<<EB, 256, 0, stream>>>(ei, flags, offsets, cursor, csr_col);
    qagg_kernel<<<N_NODES / 4, 256, 0, stream>>>(offsets, csr_col, h_q, q_agg);
    attn_kernel<<<N_NODES / 4, 256, 0, stream>>>(offsets, csr_col, k_act, q_agg,
                                                 h_projb, out);
}